// Round 1
// baseline (1101.127 us; speedup 1.0000x reference)
//
#include <hip/hip_runtime.h>
#include <hip/hip_bf16.h>

#define B_TOTAL 4096
#define N_NODES 64
#define F_IN 6
#define HID 128
#define MB 32   // batches per scan block

__device__ __forceinline__ float sigm(float x) { return 1.0f / (1.0f + expf(-x)); }

// ---------------- Kernel A: neighbor mean ----------------
__global__ __launch_bounds__(256) void k_neighbor_mean(
    const float* __restrict__ matrix,   // [B,64,64]
    const float* __restrict__ features, // [B,64,6]
    float* __restrict__ upd)            // [B,64,6]
{
    __shared__ float adj[64][65];
    __shared__ float fx[64][6];
    const int b = blockIdx.x;
    const int tid = threadIdx.x;
    const float* mb_ = matrix + (size_t)b * 4096;
    for (int idx = tid; idx < 4096; idx += 256) adj[idx >> 6][idx & 63] = mb_[idx];
    const float* fb = features + (size_t)b * 384;
    for (int idx = tid; idx < 384; idx += 256) fx[idx / 6][idx % 6] = fb[idx];
    __syncthreads();
    if (tid < 64) {
        const int i = tid;
        float s0=0,s1=0,s2=0,s3=0,s4=0,s5=0,cnt=0;
        for (int j = 0; j < 64; j++) {
            float m = adj[i][j] > 0.0f ? 1.0f : 0.0f;
            cnt += m;
            s0 += m*fx[j][0]; s1 += m*fx[j][1]; s2 += m*fx[j][2];
            s3 += m*fx[j][3]; s4 += m*fx[j][4]; s5 += m*fx[j][5];
        }
        const float inv = 1.0f / (cnt + 1.0f);
        float* o = upd + (size_t)b * 384 + i * 6;
        o[0]=(s0+fx[i][0])*inv; o[1]=(s1+fx[i][1])*inv; o[2]=(s2+fx[i][2])*inv;
        o[3]=(s3+fx[i][3])*inv; o[4]=(s4+fx[i][4])*inv; o[5]=(s5+fx[i][5])*inv;
    }
}

// ---------------- Kernel W: weight re-layout ----------------
// Wq  [2][128][128][4] : Wq[dir][k][hu][g]  = Wh_dir[(g*128+hu)*128 + k]
// Wiq [2][6][128][4]   : Wiq[dir][f][hu][g] = Wi_dir[(g*128+hu)*6 + f]
// bq  [2][128][4]      : bq[dir][hu][g]     = bi[g*128+hu] + bh[g*128+hu]
__global__ __launch_bounds__(256) void k_wprep(
    const float* __restrict__ Wi_f, const float* __restrict__ Wh_f,
    const float* __restrict__ bi_f, const float* __restrict__ bh_f,
    const float* __restrict__ Wi_b, const float* __restrict__ Wh_b,
    const float* __restrict__ bi_b, const float* __restrict__ bh_b,
    float* __restrict__ Wq, float* __restrict__ Wiq, float* __restrict__ bq)
{
    const int idx = blockIdx.x * 256 + threadIdx.x;   // 0 .. 131071
    {
        const int dir = idx >> 16;
        const int r = idx & 65535;
        const int g = r & 3, hu = (r >> 2) & 127, k = r >> 9;
        const float* Wh = dir ? Wh_b : Wh_f;
        Wq[idx] = Wh[(g * 128 + hu) * 128 + k];
    }
    if (idx < 2 * 6 * 128 * 4) {
        const int dir = idx / 3072;
        const int r = idx % 3072;
        const int g = r & 3, hu = (r >> 2) & 127, f = r >> 9;
        const float* Wi = dir ? Wi_b : Wi_f;
        Wiq[idx] = Wi[(g * 128 + hu) * 6 + f];
    }
    if (idx < 2 * 128 * 4) {
        const int dir = idx / 512;
        const int r = idx % 512;
        const int g = r & 3, hu = r >> 2;
        const float* bi = dir ? bi_b : bi_f;
        const float* bh = dir ? bh_b : bh_f;
        bq[idx] = bi[g * 128 + hu] + bh[g * 128 + hu];
    }
}

// ---------------- Kernel B: persistent bi-LSTM scan ----------------
// grid (B/MB, 2), block 512. Thread owns (hu = tid&127, 8 batches mb0..mb0+7).
__global__ __launch_bounds__(512) void k_lstm(
    const float* __restrict__ upd,   // [B,64,6]
    const float* __restrict__ Wq,    // [2][128][128][4]
    const float* __restrict__ Wiq,   // [2][6][128][4]
    const float* __restrict__ bq,    // [2][128][4]
    float* __restrict__ hout)        // [2][B][128]
{
    __shared__ float h_lds[MB][HID];        // 16 KB
    __shared__ float u_lds[MB][64][6];      // 48 KB
    const int tid = threadIdx.x;
    const int dir = blockIdx.y;
    const int b0 = blockIdx.x * MB;
    const int hu = tid & 127;
    const int mb0 = (tid >> 7) * 8;

    const float4* __restrict__ Wq4 = (const float4*)(Wq + dir * 65536); // [128][128]

    float4 wi[6];
    #pragma unroll
    for (int f = 0; f < 6; f++) wi[f] = ((const float4*)(Wiq + dir * 3072))[f * 128 + hu];
    const float4 bias = ((const float4*)(bq + dir * 512))[hu];

    // stage upd for this block's batches
    for (int idx = tid; idx < MB * 384; idx += 512)
        u_lds[idx / 384][(idx % 384) / 6][idx % 6] = upd[(size_t)b0 * 384 + idx];
    // zero h
    for (int idx = tid; idx < MB * HID; idx += 512) h_lds[idx >> 7][idx & 127] = 0.0f;

    float c[8];
    #pragma unroll
    for (int p = 0; p < 8; p++) c[p] = 0.0f;
    __syncthreads();

    for (int step = 0; step < 64; step++) {
        const int t = dir ? (63 - step) : step;
        float4 acc[8];
        #pragma unroll
        for (int p = 0; p < 8; p++) {
            float4 a = bias;
            #pragma unroll
            for (int f = 0; f < 6; f++) {
                const float u = u_lds[mb0 + p][t][f];
                a.x += wi[f].x * u; a.y += wi[f].y * u;
                a.z += wi[f].z * u; a.w += wi[f].w * u;
            }
            acc[p] = a;
        }
        // z += Wh @ h  over k
        for (int k = 0; k < HID; k += 4) {
            const float4 w0 = Wq4[(k + 0) * 128 + hu];
            const float4 w1 = Wq4[(k + 1) * 128 + hu];
            const float4 w2 = Wq4[(k + 2) * 128 + hu];
            const float4 w3 = Wq4[(k + 3) * 128 + hu];
            #pragma unroll
            for (int p = 0; p < 8; p++) {
                const float4 hv = *(const float4*)&h_lds[mb0 + p][k];
                acc[p].x += w0.x*hv.x + w1.x*hv.y + w2.x*hv.z + w3.x*hv.w;
                acc[p].y += w0.y*hv.x + w1.y*hv.y + w2.y*hv.z + w3.y*hv.w;
                acc[p].z += w0.z*hv.x + w1.z*hv.y + w2.z*hv.z + w3.z*hv.w;
                acc[p].w += w0.w*hv.x + w1.w*hv.y + w2.w*hv.z + w3.w*hv.w;
            }
        }
        __syncthreads();   // everyone done reading h(t-1)
        #pragma unroll
        for (int p = 0; p < 8; p++) {
            const float ig = sigm(acc[p].x);
            const float fg = sigm(acc[p].y);
            const float gg = tanhf(acc[p].z);
            const float og = sigm(acc[p].w);
            c[p] = fg * c[p] + ig * gg;
            h_lds[mb0 + p][hu] = og * tanhf(c[p]);
        }
        __syncthreads();   // h(t) visible to all
    }

    #pragma unroll
    for (int p = 0; p < 8; p++)
        hout[((size_t)dir * B_TOTAL + b0 + mb0 + p) * HID + hu] = h_lds[mb0 + p][hu];
}

// ---------------- Kernel C: final FC ----------------
__global__ __launch_bounds__(256) void k_final(
    const float* __restrict__ hout,        // [2][B][128]
    const float* __restrict__ device_idx,  // [B]
    const float* __restrict__ fc_w,        // [257]
    const float* __restrict__ fc_b,        // [1]
    float* __restrict__ y)                 // [B]
{
    const int wave = threadIdx.x >> 6;
    const int lane = threadIdx.x & 63;
    const int b = blockIdx.x * 4 + wave;
    const float* hf = hout + (size_t)b * HID;
    const float* hb = hout + ((size_t)B_TOTAL + b) * HID;
    float p = fc_w[1 + lane]        * hf[lane]
            + fc_w[1 + 64 + lane]   * hf[64 + lane]
            + fc_w[129 + lane]      * hb[lane]
            + fc_w[129 + 64 + lane] * hb[64 + lane];
    #pragma unroll
    for (int off = 32; off; off >>= 1) p += __shfl_xor(p, off, 64);
    if (lane == 0) y[b] = p + fc_w[0] * device_idx[b] + fc_b[0];
}

extern "C" void kernel_launch(void* const* d_in, const int* in_sizes, int n_in,
                              void* d_out, int out_size, void* d_ws, size_t ws_size,
                              hipStream_t stream) {
    const float* device_idx = (const float*)d_in[0];
    const float* matrix     = (const float*)d_in[1];
    const float* features   = (const float*)d_in[2];
    const float* Wi_f = (const float*)d_in[3];
    const float* Wh_f = (const float*)d_in[4];
    const float* bi_f = (const float*)d_in[5];
    const float* bh_f = (const float*)d_in[6];
    const float* Wi_b = (const float*)d_in[7];
    const float* Wh_b = (const float*)d_in[8];
    const float* bi_b = (const float*)d_in[9];
    const float* bh_b = (const float*)d_in[10];
    const float* fc_w = (const float*)d_in[11];
    const float* fc_b = (const float*)d_in[12];
    float* out = (float*)d_out;

    float* ws   = (float*)d_ws;
    float* upd  = ws;                  // 4096*64*6      = 1,572,864 floats
    float* Wq   = ws + 1572864;        // 2*128*128*4    =   131,072
    float* Wiq  = ws + 1703936;        // 2*6*128*4      =     6,144
    float* bq   = ws + 1710080;        // 2*128*4        =     1,024
    float* hout = ws + 1711104;        // 2*4096*128     = 1,048,576

    hipLaunchKernelGGL(k_neighbor_mean, dim3(B_TOTAL), dim3(256), 0, stream,
                       matrix, features, upd);
    hipLaunchKernelGGL(k_wprep, dim3(512), dim3(256), 0, stream,
                       Wi_f, Wh_f, bi_f, bh_f, Wi_b, Wh_b, bi_b, bh_b, Wq, Wiq, bq);
    hipLaunchKernelGGL(k_lstm, dim3(B_TOTAL / MB, 2), dim3(512), 0, stream,
                       upd, Wq, Wiq, bq, hout);
    hipLaunchKernelGGL(k_final, dim3(B_TOTAL / 4), dim3(256), 0, stream,
                       hout, device_idx, fc_w, fc_b, out);
}

// Round 2
// 261.413 us; speedup vs baseline: 4.2122x; 4.2122x over previous
//
#include <hip/hip_runtime.h>
#include <hip/hip_bf16.h>

#define B_TOTAL 4096
#define MBATCH 32

typedef short short8 __attribute__((ext_vector_type(8)));
typedef float f32x4 __attribute__((ext_vector_type(4)));

__device__ __forceinline__ unsigned short rne_bf16(float x) {
    unsigned int u = __float_as_uint(x);
    unsigned int r = (u + 0x7fffu + ((u >> 16) & 1u)) >> 16;
    return (unsigned short)r;
}
__device__ __forceinline__ float bf16_to_f(unsigned short h) {
    return __uint_as_float(((unsigned int)h) << 16);
}
__device__ __forceinline__ float fast_sigm(float x) {
    return __builtin_amdgcn_rcpf(1.0f + __expf(-x));
}
__device__ __forceinline__ float fast_tanh(float x) {
    return 1.0f - 2.0f * __builtin_amdgcn_rcpf(1.0f + __expf(2.0f * x));
}

// ---------------- Kernel A: neighbor mean ----------------
__global__ __launch_bounds__(256) void k_neighbor_mean(
    const float* __restrict__ matrix,   // [B,64,64]
    const float* __restrict__ features, // [B,64,6]
    float* __restrict__ upd)            // [B,64,6]
{
    __shared__ float adj[64][65];
    __shared__ float fx[64][6];
    const int b = blockIdx.x;
    const int tid = threadIdx.x;
    const float* mb_ = matrix + (size_t)b * 4096;
    for (int idx = tid; idx < 4096; idx += 256) adj[idx >> 6][idx & 63] = mb_[idx];
    const float* fb = features + (size_t)b * 384;
    for (int idx = tid; idx < 384; idx += 256) fx[idx / 6][idx % 6] = fb[idx];
    __syncthreads();
    if (tid < 64) {
        const int i = tid;
        float s0=0,s1=0,s2=0,s3=0,s4=0,s5=0,cnt=0;
        for (int j = 0; j < 64; j++) {
            float m = adj[i][j] > 0.0f ? 1.0f : 0.0f;
            cnt += m;
            s0 += m*fx[j][0]; s1 += m*fx[j][1]; s2 += m*fx[j][2];
            s3 += m*fx[j][3]; s4 += m*fx[j][4]; s5 += m*fx[j][5];
        }
        const float inv = 1.0f / (cnt + 1.0f);
        float* o = upd + (size_t)b * 384 + i * 6;
        o[0]=(s0+fx[i][0])*inv; o[1]=(s1+fx[i][1])*inv; o[2]=(s2+fx[i][2])*inv;
        o[3]=(s3+fx[i][3])*inv; o[4]=(s4+fx[i][4])*inv; o[5]=(s5+fx[i][5])*inv;
    }
}

// ---------------- Kernel W: weights -> A-fragment layout, bf16 hi/lo ----------------
// Aw[dir 2][mtg 32][kc 5][s 2][lane 64][e 8] bf16  (327680 ushorts)
// A'(n,k): n = mtg*16 + (lane&15) (gate-interleaved n = 4*hu+g), k = kc*32 + 8*(lane>>4)+e
// kc<4: Wh[j][k]; kc==4: k-local 0..5 -> Wi[j][kk], 6 -> bi[j]+bh[j], else 0.  j = (n&3)*128 + (n>>2)
__global__ __launch_bounds__(256) void k_wprep2(
    const float* __restrict__ Wi_f, const float* __restrict__ Wh_f,
    const float* __restrict__ bi_f, const float* __restrict__ bh_f,
    const float* __restrict__ Wi_b, const float* __restrict__ Wh_b,
    const float* __restrict__ bi_b, const float* __restrict__ bh_b,
    unsigned short* __restrict__ Aw)
{
    const int idx = blockIdx.x * 256 + threadIdx.x;   // 0..327679
    const int dir = idx / 163840;
    const int r   = idx % 163840;
    const int mt  = r / 5120;
    const int r2  = r % 5120;
    const int kc  = r2 / 1024;
    const int r3  = r2 % 1024;
    const int s   = r3 >> 9;
    const int l   = (r3 >> 3) & 63;
    const int e   = r3 & 7;
    const int n   = mt * 16 + (l & 15);
    const int j   = (n & 3) * 128 + (n >> 2);
    const float* Wh = dir ? Wh_b : Wh_f;
    const float* Wi = dir ? Wi_b : Wi_f;
    const float* bi = dir ? bi_b : bi_f;
    const float* bh = dir ? bh_b : bh_f;
    float w;
    if (kc < 4) {
        const int k = kc * 32 + 8 * (l >> 4) + e;
        w = Wh[j * 128 + k];
    } else {
        const int kk = 8 * (l >> 4) + e;
        w = kk < 6 ? Wi[j * 6 + kk] : (kk == 6 ? (bi[j] + bh[j]) : 0.0f);
    }
    const unsigned short hi = rne_bf16(w);
    unsigned short out = hi;
    if (s) out = rne_bf16(w - bf16_to_f(hi));
    Aw[idx] = out;
}

// ---------------- Kernel B: MFMA bi-LSTM scan ----------------
// grid (128, 2), block 512 (8 waves). Z^T = A'(W, M=512 gates) x B'(h^T, N=32 batches), K=160.
// Wave owns mtg = wave*4..wave*4+3 (hu block [wave*16, wave*16+16)), both 16-batch ntiles.
__global__ __launch_bounds__(512, 2) void k_lstm2(
    const float* __restrict__ upd,          // [4096][64][6]
    const unsigned short* __restrict__ Aw,  // [2][32][5][2][64][8]
    float* __restrict__ hout)               // [2][4096][128]
{
    __shared__ unsigned short h_hi[32 * 128];   // 8 KB, row b = 256 B = 16 chunks, XOR-swz by (b&7)
    __shared__ unsigned short h_lo[32 * 128];   // 8 KB
    const int tid  = threadIdx.x;
    const int wave = tid >> 6;
    const int lane = tid & 63;
    const int dir  = blockIdx.y;
    const int b0   = blockIdx.x * MBATCH;
    const int l15  = lane & 15;
    const int lhi  = lane >> 4;

    // persistent weight A-fragments: 4 mtg x 5 kc x {hi,lo} = 160 VGPRs
    short8 aw[4][5][2];
    {
        const unsigned short* base = Aw + (size_t)dir * 163840;
        #pragma unroll
        for (int mt = 0; mt < 4; mt++)
            #pragma unroll
            for (int kc = 0; kc < 5; kc++)
                #pragma unroll
                for (int s = 0; s < 2; s++) {
                    const int mtg = wave * 4 + mt;
                    const unsigned short* p = base + (((size_t)(mtg * 5 + kc) * 2 + s) * 64 + lane) * 8;
                    aw[mt][kc][s] = *(const short8*)p;
                }
    }
    // zero h state in LDS
    #pragma unroll
    for (int i = 0; i < 4; i++) {
        ((int*)h_hi)[tid + 512 * i] = 0;
        ((int*)h_lo)[tid + 512 * i] = 0;
    }
    float c[8];
    #pragma unroll
    for (int p = 0; p < 8; p++) c[p] = 0.0f;
    __syncthreads();

    const f32x4 zero4 = {0.0f, 0.0f, 0.0f, 0.0f};

    for (int step = 0; step < 64; step++) {
        const int t = dir ? (63 - step) : step;

        // ---- build u-chunk B' fragments (k-local 0..5 = u feats, 6 = 1.0, rest 0) ----
        short8 bu_h[2], bu_l[2];
        #pragma unroll
        for (int nt = 0; nt < 2; nt++) {
            float v[8];
            #pragma unroll
            for (int e = 0; e < 8; e++) v[e] = 0.0f;
            if (lhi == 0) {
                const int b = nt * 16 + l15;
                const float2* up = (const float2*)(upd + (size_t)(b0 + b) * 384 + t * 6);
                const float2 a0 = up[0], a1 = up[1], a2 = up[2];
                v[0] = a0.x; v[1] = a0.y; v[2] = a1.x;
                v[3] = a1.y; v[4] = a2.x; v[5] = a2.y;
                v[6] = 1.0f;
            }
            short8 vh, vl;
            #pragma unroll
            for (int e = 0; e < 8; e++) {
                const unsigned short hh = rne_bf16(v[e]);
                vh[e] = (short)hh;
                vl[e] = (short)rne_bf16(v[e] - bf16_to_f(hh));
            }
            bu_h[nt] = vh; bu_l[nt] = vl;
        }

        // ---- MFMA: init with u-chunk (3 passes), then 4 h-chunks (3 passes each) ----
        f32x4 acc[4][2];
        #pragma unroll
        for (int mt = 0; mt < 4; mt++)
            #pragma unroll
            for (int nt = 0; nt < 2; nt++) {
                f32x4 a = __builtin_amdgcn_mfma_f32_16x16x32_bf16(aw[mt][4][0], bu_h[nt], zero4, 0, 0, 0);
                a = __builtin_amdgcn_mfma_f32_16x16x32_bf16(aw[mt][4][0], bu_l[nt], a, 0, 0, 0);
                a = __builtin_amdgcn_mfma_f32_16x16x32_bf16(aw[mt][4][1], bu_h[nt], a, 0, 0, 0);
                acc[mt][nt] = a;
            }
        #pragma unroll
        for (int kc = 0; kc < 4; kc++) {
            const int chunk = kc * 4 + lhi;
            const int by0 = l15 * 256 + ((chunk ^ (l15 & 7)) << 4);
            const int b1  = 16 + l15;
            const int by1 = b1 * 256 + ((chunk ^ (b1 & 7)) << 4);
            const short8 bh0 = *(const short8*)((const char*)h_hi + by0);
            const short8 bl0 = *(const short8*)((const char*)h_lo + by0);
            const short8 bh1 = *(const short8*)((const char*)h_hi + by1);
            const short8 bl1 = *(const short8*)((const char*)h_lo + by1);
            #pragma unroll
            for (int mt = 0; mt < 4; mt++) {
                acc[mt][0] = __builtin_amdgcn_mfma_f32_16x16x32_bf16(aw[mt][kc][0], bh0, acc[mt][0], 0, 0, 0);
                acc[mt][0] = __builtin_amdgcn_mfma_f32_16x16x32_bf16(aw[mt][kc][0], bl0, acc[mt][0], 0, 0, 0);
                acc[mt][0] = __builtin_amdgcn_mfma_f32_16x16x32_bf16(aw[mt][kc][1], bh0, acc[mt][0], 0, 0, 0);
                acc[mt][1] = __builtin_amdgcn_mfma_f32_16x16x32_bf16(aw[mt][kc][0], bh1, acc[mt][1], 0, 0, 0);
                acc[mt][1] = __builtin_amdgcn_mfma_f32_16x16x32_bf16(aw[mt][kc][0], bl1, acc[mt][1], 0, 0, 0);
                acc[mt][1] = __builtin_amdgcn_mfma_f32_16x16x32_bf16(aw[mt][kc][1], bh1, acc[mt][1], 0, 0, 0);
            }
        }
        __syncthreads();   // BAR1: all waves done reading h(t-1)

        // ---- phase B: lane-local cell update; D reg i == gate i for (b, hu) ----
        #pragma unroll
        for (int mt = 0; mt < 4; mt++)
            #pragma unroll
            for (int nt = 0; nt < 2; nt++) {
                const int p = mt * 2 + nt;
                const f32x4 z = acc[mt][nt];
                const float ig = fast_sigm(z[0]);
                const float fg = fast_sigm(z[1]);
                const float gg = fast_tanh(z[2]);
                const float og = fast_sigm(z[3]);
                const float cc = fg * c[p] + ig * gg;
                c[p] = cc;
                const float h = og * fast_tanh(cc);
                const int hu = wave * 16 + mt * 4 + lhi;
                const int b  = nt * 16 + l15;
                const unsigned short hh = rne_bf16(h);
                const unsigned short hl = rne_bf16(h - bf16_to_f(hh));
                const int byte_off = b * 256 + (((hu >> 3) ^ (b & 7)) << 4) + (hu & 7) * 2;
                *(unsigned short*)((char*)h_hi + byte_off) = hh;
                *(unsigned short*)((char*)h_lo + byte_off) = hl;
                if (step == 63)
                    hout[((size_t)dir * B_TOTAL + b0 + b) * 128 + hu] = h;
            }
        __syncthreads();   // BAR2: h(t) visible to all
    }
}

// ---------------- Kernel C: final FC ----------------
__global__ __launch_bounds__(256) void k_final(
    const float* __restrict__ hout,        // [2][B][128]
    const float* __restrict__ device_idx,  // [B]
    const float* __restrict__ fc_w,        // [257]
    const float* __restrict__ fc_b,        // [1]
    float* __restrict__ y)                 // [B]
{
    const int wave = threadIdx.x >> 6;
    const int lane = threadIdx.x & 63;
    const int b = blockIdx.x * 4 + wave;
    const float* hf = hout + (size_t)b * 128;
    const float* hb = hout + ((size_t)B_TOTAL + b) * 128;
    float p = fc_w[1 + lane]        * hf[lane]
            + fc_w[1 + 64 + lane]   * hf[64 + lane]
            + fc_w[129 + lane]      * hb[lane]
            + fc_w[129 + 64 + lane] * hb[64 + lane];
    #pragma unroll
    for (int off = 32; off; off >>= 1) p += __shfl_xor(p, off, 64);
    if (lane == 0) y[b] = p + fc_w[0] * device_idx[b] + fc_b[0];
}

extern "C" void kernel_launch(void* const* d_in, const int* in_sizes, int n_in,
                              void* d_out, int out_size, void* d_ws, size_t ws_size,
                              hipStream_t stream) {
    const float* device_idx = (const float*)d_in[0];
    const float* matrix     = (const float*)d_in[1];
    const float* features   = (const float*)d_in[2];
    const float* Wi_f = (const float*)d_in[3];
    const float* Wh_f = (const float*)d_in[4];
    const float* bi_f = (const float*)d_in[5];
    const float* bh_f = (const float*)d_in[6];
    const float* Wi_b = (const float*)d_in[7];
    const float* Wh_b = (const float*)d_in[8];
    const float* bi_b = (const float*)d_in[9];
    const float* bh_b = (const float*)d_in[10];
    const float* fc_w = (const float*)d_in[11];
    const float* fc_b = (const float*)d_in[12];
    float* out = (float*)d_out;

    float* ws = (float*)d_ws;
    float*          upd  = ws;                               // 1,572,864 floats
    unsigned short* Aw   = (unsigned short*)(ws + 1572864);  // 327,680 ushorts (163,840 float slots)
    float*          hout = ws + 1736704;                     // 1,048,576 floats

    hipLaunchKernelGGL(k_neighbor_mean, dim3(B_TOTAL), dim3(256), 0, stream,
                       matrix, features, upd);
    hipLaunchKernelGGL(k_wprep2, dim3(1280), dim3(256), 0, stream,
                       Wi_f, Wh_f, bi_f, bh_f, Wi_b, Wh_b, bi_b, bh_b, Aw);
    hipLaunchKernelGGL(k_lstm2, dim3(B_TOTAL / MBATCH, 2), dim3(512), 0, stream,
                       upd, Aw, hout);
    hipLaunchKernelGGL(k_final, dim3(B_TOTAL / 4), dim3(256), 0, stream,
                       hout, device_idx, fc_w, fc_b, out);
}